// Round 5
// baseline (485.781 us; speedup 1.0000x reference)
//
#include <hip/hip_runtime.h>
#include <math.h>

// Problem constants (fixed by reference setup_inputs)
constexpr int B = 2, C = 16, H = 160, W = 192, S = 3, D = 48;
constexpr int HW = H * W;          // 30720 = 120 * 256
constexpr int SB = S * B;

// ------------------------------------------------------------------
// Setup kernel: per (s,b) fold projection chain into
//   A = Ks * R * inv(Kref) (3x3 f64), q = Ks * t (f64)
// so main kernel does p = depth*(A*[u,v,1]) + q.
// ws layout: (s*B+b)*12 doubles = [A row-major 0..8][q 9..11]
// ------------------------------------------------------------------
__global__ void precompute_mats(const float* __restrict__ ref_intr,
                                const float* __restrict__ src_intr,
                                const float* __restrict__ ref_to_src,
                                double* __restrict__ ws)
{
    const int i = threadIdx.x;
    if (i >= SB) return;
    const int b = i % B;

    const float* Kp = ref_intr + b * 9;
    const double a00 = Kp[0], a01 = Kp[1], a02 = Kp[2];
    const double a10 = Kp[3], a11 = Kp[4], a12 = Kp[5];
    const double a20 = Kp[6], a21 = Kp[7], a22 = Kp[8];
    const double c00 =  (a11 * a22 - a12 * a21);
    const double c01 = -(a10 * a22 - a12 * a20);
    const double c02 =  (a10 * a21 - a11 * a20);
    const double c10 = -(a01 * a22 - a02 * a21);
    const double c11 =  (a00 * a22 - a02 * a20);
    const double c12 = -(a00 * a21 - a01 * a20);
    const double c20 =  (a01 * a12 - a02 * a11);
    const double c21 = -(a00 * a12 - a02 * a10);
    const double c22 =  (a00 * a11 - a01 * a10);
    const double invdet = 1.0 / (a00 * c00 + a01 * c01 + a02 * c02);
    const double iK[9] = { c00 * invdet, c10 * invdet, c20 * invdet,
                           c01 * invdet, c11 * invdet, c21 * invdet,
                           c02 * invdet, c12 * invdet, c22 * invdet };

    const float* Tp = ref_to_src + i * 16;
    const float* Ks = src_intr + i * 9;

    double M[9];  // R * inv(K)
    #pragma unroll
    for (int r = 0; r < 3; ++r)
        #pragma unroll
        for (int c = 0; c < 3; ++c)
            M[r * 3 + c] = (double)Tp[r * 4 + 0] * iK[0 + c]
                         + (double)Tp[r * 4 + 1] * iK[3 + c]
                         + (double)Tp[r * 4 + 2] * iK[6 + c];

    double* o = ws + i * 12;
    #pragma unroll
    for (int r = 0; r < 3; ++r) {
        #pragma unroll
        for (int c = 0; c < 3; ++c)
            o[r * 3 + c] = (double)Ks[r * 3 + 0] * M[0 + c]
                         + (double)Ks[r * 3 + 1] * M[3 + c]
                         + (double)Ks[r * 3 + 2] * M[6 + c];
        o[9 + r] = (double)Ks[r * 3 + 0] * (double)Tp[3]
                 + (double)Ks[r * 3 + 1] * (double)Tp[7]
                 + (double)Ks[r * 3 + 2] * (double)Tp[11];
    }
}

// ------------------------------------------------------------------
// Main kernel. 2D grid (Round-4 win): blockIdx.y = b*D+d makes b/d/s
// provably wave-uniform -> channel bases scalarize (saddr loads).
// Round-5 changes:
//  * single fused NCC pass: shifted variance (shift = f2[0]) kills the
//    f2[16] array -> target VGPR <= 64 (the m69 occupancy cliff:
//    72 regs = 4 waves/SIMD, 64 regs = 8).
//      sq2 = Σ(t - t̄)², t = f2c - f2[0]  -- exact identity; safe where
//      E[x²]-E[x]² cancels, because the O(1) offset is removed BEFORE
//      squaring (Sterbenz), so abs error ~ ulp(n2²) not ulp(m2²·C).
//      dot = Σ f1c·f2c exactly (Σf1 = 0 by construction, residual ~4e-7).
//  * fractions/weights in f32 after the f64 projection (x,y already
//    ~1e-12-accurate; weight err ~1e-6 << 3.9e-3 tol).
//  * one Newton step on v_rcp_f64 (base >= 2^-14 -> >= 2^-28 rel).
//  * __launch_bounds__(256,8): MILD cap (natural ~55-65). Tripwire:
//    WRITE_SIZE >> 11.5 MB means spill -> remove the bound.
// ------------------------------------------------------------------
__global__ __launch_bounds__(256, 8) void plane_sweep_kernel(
    const float* __restrict__ ref_feats,   // [B,C,H,W]
    const float* __restrict__ src_feats,   // [S,B,C,H,W]
    const float* __restrict__ depths,      // [D]
    const double* __restrict__ mats,       // [SB][12]
    float* __restrict__ out)               // [B,D,H,W]
{
    const int pix = blockIdx.x * 256 + threadIdx.x;   // HW = 120*256 exact
    const int by  = blockIdx.y;                       // b*D + d (scalar)
    const int d   = by % D;                           // scalar
    const int b   = by / D;                           // scalar

    const int w = pix % W;
    const int h = pix / W;

    // ---- ref fragment: load, zero-mean, norm (f32, well-conditioned) ----
    const float* rb = ref_feats + (size_t)b * C * HW;
    float f1[C];
    float sum1 = 0.0f;
    #pragma unroll
    for (int c = 0; c < C; ++c) { f1[c] = rb[c * HW + pix]; sum1 += f1[c]; }
    const float m1 = sum1 * (1.0f / C);
    float sq1 = 0.0f;
    #pragma unroll
    for (int c = 0; c < C; ++c) { f1[c] -= m1; sq1 = fmaf(f1[c], f1[c], sq1); }
    const float n1 = sqrtf(sq1);

    const double u = (double)w, v = (double)h;
    const double depth = (double)depths[d];    // scalar load
    float cost = 0.0f;

    #pragma unroll 1   // one source's f64 state live at a time; s uniform
    for (int s = 0; s < S; ++s) {
        const double* Aq = mats + (s * B + b) * 12;   // scalar loads
        const double rx = fma(u, Aq[0], fma(v, Aq[1], Aq[2]));
        const double ry = fma(u, Aq[3], fma(v, Aq[4], Aq[5]));
        const double rz = fma(u, Aq[6], fma(v, Aq[7], Aq[8]));

        const double p0 = fma(depth, rx, Aq[9]);
        const double p1 = fma(depth, ry, Aq[10]);
        const double p2 = fma(depth, rz, Aq[11]);

        const bool valid = p2 > 0.001;
        const double zs = fmax(p2, 0.001);
        // f64 reciprocal: v_rcp_f64 approx + 1 Newton step
#if __has_builtin(__builtin_amdgcn_rcp)
        double r = __builtin_amdgcn_rcp(zs);
#else
        double r = (double)__builtin_amdgcn_rcpf((float)zs);
        r = r * fma(-zs, r, 2.0);
#endif
        r = r * fma(-zs, r, 2.0);
        const double x = p0 * r;
        const double y = p1 * r;

        const double x0f = floor(x);
        const double y0f = floor(y);
        // sub-pixel fractions -> f32 (f64 x,y already exact to ~1e-12)
        const float fx = (float)(x - x0f);
        const float fy = (float)(y - y0f);
        const int x0 = (int)x0f;
        const int y0 = (int)y0f;
        const int x1 = x0 + 1;
        const int y1 = y0 + 1;

        const float gx = 1.0f - fx, gy = 1.0f - fy;
        const bool okx0 = (x0 >= 0) & (x0 < W);
        const bool okx1 = (x1 >= 0) & (x1 < W);
        const bool oky0 = (y0 >= 0) & (y0 < H);
        const bool oky1 = (y1 >= 0) & (y1 < H);
        const float w00 = (valid & okx0 & oky0) ? gx * gy : 0.0f;
        const float w01 = (valid & okx1 & oky0) ? fx * gy : 0.0f;
        const float w10 = (valid & okx0 & oky1) ? gx * fy : 0.0f;
        const float w11 = (valid & okx1 & oky1) ? fx * fy : 0.0f;

        const int x0c = min(max(x0, 0), W - 1);
        const int x1c = min(max(x1, 0), W - 1);
        const int y0c = min(max(y0, 0), H - 1);
        const int y1c = min(max(y1, 0), H - 1);
        const int off00 = y0c * W + x0c;
        const int off01 = y0c * W + x1c;
        const int off10 = y1c * W + x0c;
        const int off11 = y1c * W + x1c;

        // sb wave-uniform -> saddr loads sharing 4 voffsets
        const float* sb = src_feats + (size_t)(s * B + b) * C * HW;

        // single fused pass: bilinear + shifted-variance stats + dot
        float dot = 0.0f, st = 0.0f, s2 = 0.0f, aval = 0.0f;
        #pragma unroll
        for (int c = 0; c < C; ++c) {
            const float v00 = sb[c * HW + off00];
            const float v01 = sb[c * HW + off01];
            const float v10 = sb[c * HW + off10];
            const float v11 = sb[c * HW + off11];
            const float val = w00 * v00 + w01 * v01 + w10 * v10 + w11 * v11;
            if (c == 0) {
                aval = val;            // shift; t_0 = 0 contributes nothing
            } else {
                const float t = val - aval;
                st += t;
                s2 = fmaf(t, t, s2);
            }
            dot = fmaf(f1[c], val, dot);   // exact: Σf1 = 0
        }
        // Σ(f2-m2)^2 = s2 - st^2/C  (shifted form; clamp rounding negatives)
        float sq2 = fmaf(-st * (1.0f / C), st, s2);
        sq2 = fmaxf(sq2, 0.0f);
        const float den = n1 * sqrtf(sq2) + 1e-6f;
        cost += dot / den;
    }

    out[(size_t)by * HW + pix] = cost * (1.0f / S);
}

extern "C" void kernel_launch(void* const* d_in, const int* in_sizes, int n_in,
                              void* d_out, int out_size, void* d_ws, size_t ws_size,
                              hipStream_t stream) {
    const float* ref_feats  = (const float*)d_in[0];
    const float* src_feats  = (const float*)d_in[1];
    const float* ref_intr   = (const float*)d_in[2];
    const float* src_intr   = (const float*)d_in[3];
    const float* ref_to_src = (const float*)d_in[4];
    const float* depths     = (const float*)d_in[5];
    float* out = (float*)d_out;
    double* mats = (double*)d_ws;   // needs SB*12*8 = 576 bytes

    precompute_mats<<<1, 64, 0, stream>>>(ref_intr, src_intr, ref_to_src, mats);

    dim3 grid(HW / 256, B * D);     // 120 x 96, exact
    plane_sweep_kernel<<<grid, dim3(256), 0, stream>>>(
        ref_feats, src_feats, depths, mats, out);
}

// Round 6
// 164.750 us; speedup vs baseline: 2.9486x; 2.9486x over previous
//
#include <hip/hip_runtime.h>
#include <math.h>

// Problem constants (fixed by reference setup_inputs)
constexpr int B = 2, C = 16, H = 160, W = 192, S = 3, D = 48;
constexpr int HW = H * W;          // 30720 = 120 * 256
constexpr int SB = S * B;

// ------------------------------------------------------------------
// Setup kernel: per (s,b) fold projection chain into
//   A = Ks * R * inv(Kref) (3x3 f64), q = Ks * t (f64)
// so main kernel does p = depth*(A*[u,v,1]) + q.
// ws layout: (s*B+b)*12 doubles = [A row-major 0..8][q 9..11]
// ------------------------------------------------------------------
__global__ void precompute_mats(const float* __restrict__ ref_intr,
                                const float* __restrict__ src_intr,
                                const float* __restrict__ ref_to_src,
                                double* __restrict__ ws)
{
    const int i = threadIdx.x;
    if (i >= SB) return;
    const int b = i % B;

    const float* Kp = ref_intr + b * 9;
    const double a00 = Kp[0], a01 = Kp[1], a02 = Kp[2];
    const double a10 = Kp[3], a11 = Kp[4], a12 = Kp[5];
    const double a20 = Kp[6], a21 = Kp[7], a22 = Kp[8];
    const double c00 =  (a11 * a22 - a12 * a21);
    const double c01 = -(a10 * a22 - a12 * a20);
    const double c02 =  (a10 * a21 - a11 * a20);
    const double c10 = -(a01 * a22 - a02 * a21);
    const double c11 =  (a00 * a22 - a02 * a20);
    const double c12 = -(a00 * a21 - a01 * a20);
    const double c20 =  (a01 * a12 - a02 * a11);
    const double c21 = -(a00 * a12 - a02 * a10);
    const double c22 =  (a00 * a11 - a01 * a10);
    const double invdet = 1.0 / (a00 * c00 + a01 * c01 + a02 * c02);
    const double iK[9] = { c00 * invdet, c10 * invdet, c20 * invdet,
                           c01 * invdet, c11 * invdet, c21 * invdet,
                           c02 * invdet, c12 * invdet, c22 * invdet };

    const float* Tp = ref_to_src + i * 16;
    const float* Ks = src_intr + i * 9;

    double M[9];  // R * inv(K)
    #pragma unroll
    for (int r = 0; r < 3; ++r)
        #pragma unroll
        for (int c = 0; c < 3; ++c)
            M[r * 3 + c] = (double)Tp[r * 4 + 0] * iK[0 + c]
                         + (double)Tp[r * 4 + 1] * iK[3 + c]
                         + (double)Tp[r * 4 + 2] * iK[6 + c];

    double* o = ws + i * 12;
    #pragma unroll
    for (int r = 0; r < 3; ++r) {
        #pragma unroll
        for (int c = 0; c < 3; ++c)
            o[r * 3 + c] = (double)Ks[r * 3 + 0] * M[0 + c]
                         + (double)Ks[r * 3 + 1] * M[3 + c]
                         + (double)Ks[r * 3 + 2] * M[6 + c];
        o[9 + r] = (double)Ks[r * 3 + 0] * (double)Tp[3]
                 + (double)Ks[r * 3 + 1] * (double)Tp[7]
                 + (double)Ks[r * 3 + 2] * (double)Tp[11];
    }
}

// ------------------------------------------------------------------
// Main kernel. 2D grid (Round-4 win): blockIdx.y = b*D+d makes b/d/s
// provably wave-uniform -> depth/mats/channel-bases scalarize (saddr
// loads, SALU address arith). NCHW stride-1 coalesced loads (Round-3
// lesson: NHWC per-thread 64B gathers amplify L1 transactions ~4x).
//
// Register policy (Rounds 2 & 5, HARD RULE for this kernel): NO
// min-waves __launch_bounds__ — any forced cap sends f1[]/addressing
// state to scratch (WRITE_SIZE 11.5MB -> ~1GB, 4x slowdown). Natural
// allocation is the working point; pressure reduced instead by the
// fused single-pass NCC below (validated absmax 0.0039 in Round 5):
//  * shifted variance (shift = f2[0]): sq2 = Σt² - (Σt)²/C with
//    t = f2c - f2[0] — exact identity, cancellation-safe (offset is
//    removed BEFORE squaring), kills the f2[16] array.
//  * dot = Σ f1c·f2c directly (Σf1 = 0 by construction).
//  * fractions/weights f32 after f64 projection; 1-Newton rcp_f64.
// ------------------------------------------------------------------
__global__ __launch_bounds__(256) void plane_sweep_kernel(
    const float* __restrict__ ref_feats,   // [B,C,H,W]
    const float* __restrict__ src_feats,   // [S,B,C,H,W]
    const float* __restrict__ depths,      // [D]
    const double* __restrict__ mats,       // [SB][12]
    float* __restrict__ out)               // [B,D,H,W]
{
    const int pix = blockIdx.x * 256 + threadIdx.x;   // HW = 120*256 exact
    const int by  = blockIdx.y;                       // b*D + d (scalar)
    const int d   = by % D;                           // scalar
    const int b   = by / D;                           // scalar

    const int w = pix % W;
    const int h = pix / W;

    // ---- ref fragment: load, zero-mean, norm (f32, well-conditioned) ----
    const float* rb = ref_feats + (size_t)b * C * HW;
    float f1[C];
    float sum1 = 0.0f;
    #pragma unroll
    for (int c = 0; c < C; ++c) { f1[c] = rb[c * HW + pix]; sum1 += f1[c]; }
    const float m1 = sum1 * (1.0f / C);
    float sq1 = 0.0f;
    #pragma unroll
    for (int c = 0; c < C; ++c) { f1[c] -= m1; sq1 = fmaf(f1[c], f1[c], sq1); }
    const float n1 = sqrtf(sq1);

    const double u = (double)w, v = (double)h;
    const double depth = (double)depths[d];    // scalar load
    float cost = 0.0f;

    #pragma unroll 1   // one source's f64 state live at a time; s uniform
    for (int s = 0; s < S; ++s) {
        const double* Aq = mats + (s * B + b) * 12;   // scalar loads
        const double rx = fma(u, Aq[0], fma(v, Aq[1], Aq[2]));
        const double ry = fma(u, Aq[3], fma(v, Aq[4], Aq[5]));
        const double rz = fma(u, Aq[6], fma(v, Aq[7], Aq[8]));

        const double p0 = fma(depth, rx, Aq[9]);
        const double p1 = fma(depth, ry, Aq[10]);
        const double p2 = fma(depth, rz, Aq[11]);

        const bool valid = p2 > 0.001;
        const double zs = fmax(p2, 0.001);
        // f64 reciprocal: v_rcp_f64 approx + 1 Newton step (>=2^-28 rel)
#if __has_builtin(__builtin_amdgcn_rcp)
        double r = __builtin_amdgcn_rcp(zs);
#else
        double r = (double)__builtin_amdgcn_rcpf((float)zs);
        r = r * fma(-zs, r, 2.0);
#endif
        r = r * fma(-zs, r, 2.0);
        const double x = p0 * r;
        const double y = p1 * r;

        const double x0f = floor(x);
        const double y0f = floor(y);
        // sub-pixel fractions -> f32 (f64 x,y already ~1e-12-accurate)
        const float fx = (float)(x - x0f);
        const float fy = (float)(y - y0f);
        const int x0 = (int)x0f;
        const int y0 = (int)y0f;
        const int x1 = x0 + 1;
        const int y1 = y0 + 1;

        const float gx = 1.0f - fx, gy = 1.0f - fy;
        const bool okx0 = (x0 >= 0) & (x0 < W);
        const bool okx1 = (x1 >= 0) & (x1 < W);
        const bool oky0 = (y0 >= 0) & (y0 < H);
        const bool oky1 = (y1 >= 0) & (y1 < H);
        const float w00 = (valid & okx0 & oky0) ? gx * gy : 0.0f;
        const float w01 = (valid & okx1 & oky0) ? fx * gy : 0.0f;
        const float w10 = (valid & okx0 & oky1) ? gx * fy : 0.0f;
        const float w11 = (valid & okx1 & oky1) ? fx * fy : 0.0f;

        const int x0c = min(max(x0, 0), W - 1);
        const int x1c = min(max(x1, 0), W - 1);
        const int y0c = min(max(y0, 0), H - 1);
        const int y1c = min(max(y1, 0), H - 1);
        const int off00 = y0c * W + x0c;
        const int off01 = y0c * W + x1c;
        const int off10 = y1c * W + x0c;
        const int off11 = y1c * W + x1c;

        // sb wave-uniform -> saddr loads sharing 4 voffsets
        const float* sb = src_feats + (size_t)(s * B + b) * C * HW;

        // single fused pass: bilinear + shifted-variance stats + dot
        float dot = 0.0f, st = 0.0f, s2 = 0.0f, aval = 0.0f;
        #pragma unroll
        for (int c = 0; c < C; ++c) {
            const float v00 = sb[c * HW + off00];
            const float v01 = sb[c * HW + off01];
            const float v10 = sb[c * HW + off10];
            const float v11 = sb[c * HW + off11];
            const float val = w00 * v00 + w01 * v01 + w10 * v10 + w11 * v11;
            if (c == 0) {
                aval = val;            // shift; t_0 = 0 contributes nothing
            } else {
                const float t = val - aval;
                st += t;
                s2 = fmaf(t, t, s2);
            }
            dot = fmaf(f1[c], val, dot);   // exact: Σf1 = 0
        }
        // Σ(f2-m2)^2 = s2 - st^2/C  (shifted form; clamp rounding negatives)
        float sq2 = fmaf(-st * (1.0f / C), st, s2);
        sq2 = fmaxf(sq2, 0.0f);
        const float den = n1 * sqrtf(sq2) + 1e-6f;
        cost += dot / den;
    }

    out[(size_t)by * HW + pix] = cost * (1.0f / S);
}

extern "C" void kernel_launch(void* const* d_in, const int* in_sizes, int n_in,
                              void* d_out, int out_size, void* d_ws, size_t ws_size,
                              hipStream_t stream) {
    const float* ref_feats  = (const float*)d_in[0];
    const float* src_feats  = (const float*)d_in[1];
    const float* ref_intr   = (const float*)d_in[2];
    const float* src_intr   = (const float*)d_in[3];
    const float* ref_to_src = (const float*)d_in[4];
    const float* depths     = (const float*)d_in[5];
    float* out = (float*)d_out;
    double* mats = (double*)d_ws;   // needs SB*12*8 = 576 bytes

    precompute_mats<<<1, 64, 0, stream>>>(ref_intr, src_intr, ref_to_src, mats);

    dim3 grid(HW / 256, B * D);     // 120 x 96, exact
    plane_sweep_kernel<<<grid, dim3(256), 0, stream>>>(
        ref_feats, src_feats, depths, mats, out);
}